// Round 1
// baseline (1459.991 us; speedup 1.0000x reference)
//
#include <hip/hip_runtime.h>

// Problem constants
#define B_ 512
#define S_ 512
#define D_ 960
constexpr int H1 = 480;   // D/2
constexpr int H2 = 240;   // D/4
constexpr float INV_T = 10.0f;   // 1/temperature
constexpr float EPS_ = 1e-8f;

// ---------------------------------------------------------------------------
// 1) Mean pool over S: x[B,S,D] -> pooled[B,D].  HBM-bound: 1.0 GB read.
//    One block per b; 240 lanes x float4 = full 3840B row, coalesced.
__global__ void pool_kernel(const float* __restrict__ x, float* __restrict__ pooled) {
  const int b = blockIdx.x;
  const int t = threadIdx.x;
  if (t >= 240) return;
  const float4* __restrict__ xr = reinterpret_cast<const float4*>(x) + (size_t)b * S_ * 240;
  float4 acc = make_float4(0.f, 0.f, 0.f, 0.f);
#pragma unroll 8
  for (int s = 0; s < S_; ++s) {
    float4 v = xr[(size_t)s * 240 + t];
    acc.x += v.x; acc.y += v.y; acc.z += v.z; acc.w += v.w;
  }
  const float inv = 1.0f / S_;
  float4 o = make_float4(acc.x * inv, acc.y * inv, acc.z * inv, acc.w * inv);
  reinterpret_cast<float4*>(pooled)[(size_t)b * 240 + t] = o;
}

// ---------------------------------------------------------------------------
// 2) Layer 1: h = relu(pooled @ W1 + b1), per-half weights.
//    4 rows per block (blocks never straddle the half boundary: 256/4=64).
//    Pooled rows in LDS (wave-uniform broadcast reads); W streamed from L2.
__global__ void mlp1_kernel(const float* __restrict__ pooled,
                            const float* __restrict__ W1c, const float* __restrict__ b1c,
                            const float* __restrict__ W1a, const float* __restrict__ b1a,
                            float* __restrict__ h) {
  __shared__ float e[4 * D_];
  const int r0 = blockIdx.x * 4;
  const float* __restrict__ W    = (r0 < 256) ? W1c : W1a;
  const float* __restrict__ bias = (r0 < 256) ? b1c : b1a;
  const int t = threadIdx.x;
  {
    const float4* src = reinterpret_cast<const float4*>(pooled + (size_t)r0 * D_);
    float4* dst = reinterpret_cast<float4*>(e);
    for (int idx = t; idx < D_; idx += 256) dst[idx] = src[idx];  // 960 float4
  }
  __syncthreads();
  const int j0 = t;
  const int j1 = t + 256;
  const bool v1 = (j1 < H1);
  float acc[4][2] = {};
  const float4* e4 = reinterpret_cast<const float4*>(e);
  for (int k4 = 0; k4 < D_ / 4; ++k4) {
    float4 ev4[4];
#pragma unroll
    for (int r = 0; r < 4; ++r) ev4[r] = e4[r * (D_ / 4) + k4];
#pragma unroll
    for (int kk = 0; kk < 4; ++kk) {
      const int k = k4 * 4 + kk;
      const float w0 = W[k * H1 + j0];
      const float w1 = v1 ? W[k * H1 + j1] : 0.f;
#pragma unroll
      for (int r = 0; r < 4; ++r) {
        const float ev = (&ev4[r].x)[kk];
        acc[r][0] = fmaf(ev, w0, acc[r][0]);
        acc[r][1] = fmaf(ev, w1, acc[r][1]);
      }
    }
  }
  const float bb0 = bias[j0];
  const float bb1 = v1 ? bias[j1] : 0.f;
#pragma unroll
  for (int r = 0; r < 4; ++r) {
    h[(size_t)(r0 + r) * H1 + j0] = fmaxf(acc[r][0] + bb0, 0.f);
    if (v1) h[(size_t)(r0 + r) * H1 + j1] = fmaxf(acc[r][1] + bb1, 0.f);
  }
}

// ---------------------------------------------------------------------------
// 3) Layer 2: z = h @ W2 + b2 (no relu).  Same structure, K=480, N=240.
__global__ void mlp2_kernel(const float* __restrict__ h,
                            const float* __restrict__ W2c, const float* __restrict__ b2c,
                            const float* __restrict__ W2a, const float* __restrict__ b2a,
                            float* __restrict__ z) {
  __shared__ float e[4 * H1];
  const int r0 = blockIdx.x * 4;
  const float* __restrict__ W    = (r0 < 256) ? W2c : W2a;
  const float* __restrict__ bias = (r0 < 256) ? b2c : b2a;
  const int t = threadIdx.x;
  {
    const float4* src = reinterpret_cast<const float4*>(h + (size_t)r0 * H1);
    float4* dst = reinterpret_cast<float4*>(e);
    for (int idx = t; idx < H1; idx += 256) dst[idx] = src[idx];  // 480 float4
  }
  __syncthreads();
  if (t >= H2) return;  // no further barriers below
  float acc[4] = {};
  const float4* e4 = reinterpret_cast<const float4*>(e);
  for (int k4 = 0; k4 < H1 / 4; ++k4) {
    float4 ev4[4];
#pragma unroll
    for (int r = 0; r < 4; ++r) ev4[r] = e4[r * (H1 / 4) + k4];
#pragma unroll
    for (int kk = 0; kk < 4; ++kk) {
      const int k = k4 * 4 + kk;
      const float w = W[k * H2 + t];
#pragma unroll
      for (int r = 0; r < 4; ++r) acc[r] = fmaf((&ev4[r].x)[kk], w, acc[r]);
    }
  }
  const float bb = bias[t];
#pragma unroll
  for (int r = 0; r < 4; ++r) z[(size_t)(r0 + r) * H2 + t] = acc[r] + bb;
}

// ---------------------------------------------------------------------------
// 4) Row norms of z.  One wave per row.
__global__ void norm_kernel(const float* __restrict__ z, float* __restrict__ norms) {
  const int i = blockIdx.x;
  const int t = threadIdx.x;  // 0..63
  float s = 0.f;
  for (int k = t; k < H2; k += 64) {
    const float v = z[(size_t)i * H2 + k];
    s = fmaf(v, v, s);
  }
  for (int off = 32; off; off >>= 1) s += __shfl_down(s, off);
  if (t == 0) norms[i] = sqrtf(s);
}

// ---------------------------------------------------------------------------
// 5) Per-row: cosine-sim scores vs all 512 rows, logsumexp, nll[i].
//    Diagonal excluded (exp(NEG_INF/T - m) == 0 exactly in fp32).
//    Positive column (i-256) mod 512 == i ^ 256.
__global__ void cossim_kernel(const float* __restrict__ z, const float* __restrict__ norms,
                              float* __restrict__ nll) {
  __shared__ float zi[H2];
  __shared__ float sarr[512];
  __shared__ float red[4];
  const int i = blockIdx.x;
  const int t = threadIdx.x;
  if (t < H2 / 4)
    reinterpret_cast<float4*>(zi)[t] = reinterpret_cast<const float4*>(z + (size_t)i * H2)[t];
  __syncthreads();
  const float ni = norms[i];
  const float4* zi4 = reinterpret_cast<const float4*>(zi);
#pragma unroll
  for (int jj = 0; jj < 2; ++jj) {
    const int j = t + jj * 256;
    if (j == i) {
      sarr[j] = -1e30f;
    } else {
      const float4* zj = reinterpret_cast<const float4*>(z + (size_t)j * H2);
      float dot = 0.f;
#pragma unroll 6
      for (int k = 0; k < H2 / 4; ++k) {
        const float4 a = zj[k];
        const float4 b = zi4[k];
        dot = fmaf(a.x, b.x, dot);
        dot = fmaf(a.y, b.y, dot);
        dot = fmaf(a.z, b.z, dot);
        dot = fmaf(a.w, b.w, dot);
      }
      const float denom = fmaxf(ni * norms[j], EPS_);
      sarr[j] = dot / denom * INV_T;
    }
  }
  __syncthreads();
  // block max over 512 entries
  float m = fmaxf(sarr[t], sarr[t + 256]);
  for (int off = 32; off; off >>= 1) m = fmaxf(m, __shfl_down(m, off));
  if ((t & 63) == 0) red[t >> 6] = m;
  __syncthreads();
  const float M = fmaxf(fmaxf(red[0], red[1]), fmaxf(red[2], red[3]));
  __syncthreads();  // red reads done before reuse
  float es = expf(sarr[t] - M) + expf(sarr[t + 256] - M);
  for (int off = 32; off; off >>= 1) es += __shfl_down(es, off);
  if ((t & 63) == 0) red[t >> 6] = es;
  __syncthreads();
  if (t == 0) {
    const float total = red[0] + red[1] + red[2] + red[3];
    const float lse = logf(total) + M;
    nll[i] = lse - sarr[i ^ 256];
  }
}

// ---------------------------------------------------------------------------
// 6) Mean over 512 nll values -> scalar out.
__global__ void final_kernel(const float* __restrict__ nll, float* __restrict__ out) {
  __shared__ float red[8];
  const int t = threadIdx.x;  // block = 512
  float v = nll[t];
  for (int off = 32; off; off >>= 1) v += __shfl_down(v, off);
  if ((t & 63) == 0) red[t >> 6] = v;
  __syncthreads();
  if (t == 0) {
    float s = 0.f;
#pragma unroll
    for (int w = 0; w < 8; ++w) s += red[w];
    out[0] = s * (1.0f / 512.0f);
  }
}

// ---------------------------------------------------------------------------
extern "C" void kernel_launch(void* const* d_in, const int* in_sizes, int n_in,
                              void* d_out, int out_size, void* d_ws, size_t ws_size,
                              hipStream_t stream) {
  const float* x   = (const float*)d_in[0];
  const float* W1c = (const float*)d_in[1];
  const float* b1c = (const float*)d_in[2];
  const float* W2c = (const float*)d_in[3];
  const float* b2c = (const float*)d_in[4];
  const float* W1a = (const float*)d_in[5];
  const float* b1a = (const float*)d_in[6];
  const float* W2a = (const float*)d_in[7];
  const float* b2a = (const float*)d_in[8];
  float* ws = (float*)d_ws;

  // workspace layout (floats): total ~3.45 MB
  float* pooled = ws;                       // 512*960
  float* h      = pooled + 512 * 960;       // 512*480
  float* z      = h + 512 * 480;            // 512*240
  float* norms  = z + 512 * 240;            // 512
  float* nll    = norms + 512;              // 512
  float* out    = (float*)d_out;

  pool_kernel<<<512, 256, 0, stream>>>(x, pooled);
  mlp1_kernel<<<128, 256, 0, stream>>>(pooled, W1c, b1c, W1a, b1a, h);
  mlp2_kernel<<<128, 256, 0, stream>>>(h, W2c, b2c, W2a, b2a, z);
  norm_kernel<<<512, 64, 0, stream>>>(z, norms);
  cossim_kernel<<<512, 256, 0, stream>>>(z, norms, nll);
  final_kernel<<<1, 512, 0, stream>>>(nll, out);
}